// Round 8
// baseline (314.962 us; speedup 1.0000x reference)
//
#include <hip/hip_runtime.h>
#include <hip/hip_bf16.h>
#include <math.h>

typedef __attribute__((ext_vector_type(8))) short short8;
typedef __attribute__((ext_vector_type(4))) float floatx4;
typedef __attribute__((ext_vector_type(4))) unsigned int uintx4;
typedef __attribute__((ext_vector_type(2))) unsigned int uintx2;

__device__ __forceinline__ unsigned short f2bf(float f) {
    unsigned int u = __float_as_uint(f);
    unsigned int r = (u + 0x7fffu + ((u >> 16) & 1u)) >> 16;
    return (unsigned short)r;
}

#if defined(__has_builtin)
#if __has_builtin(__builtin_amdgcn_cvt_pk_bf16_f32)
#define HAVE_PK_BF16 1
#endif
#endif

#ifdef HAVE_PK_BF16
typedef __bf16 bf16x2_t __attribute__((ext_vector_type(2)));
__device__ __forceinline__ unsigned int pk2bf(float a, float b) {
    bf16x2_t v = __builtin_amdgcn_cvt_pk_bf16_f32(a, b);
    return __builtin_bit_cast(unsigned int, v);
}
#else
__device__ __forceinline__ unsigned int pk2bf(float a, float b) {
    unsigned int ua = __float_as_uint(a);
    ua = ua + 0x7fffu + ((ua >> 16) & 1u);
    unsigned int ub = __float_as_uint(b);
    ub = ub + 0x7fffu + ((ub >> 16) & 1u);
    return (ua >> 16) | (ub & 0xffff0000u);
}
#endif

// tanh-gelu via u*sigmoid(y), Schraudolph fast exp
__device__ __forceinline__ float gelu_f(float u) {
    float u2 = u * u;
    float y = u * fmaf(u2, 0.0713548163f, 1.5957691216f);
    y = fminf(fmaxf(y, -87.0f), 87.0f);
    float f = fmaf(y, -12102203.16f, 1064866805.0f);   // bits of e^{-y}
    float e = __int_as_float((int)f);
    return u * __builtin_amdgcn_rcpf(1.0f + e);
}

__device__ __forceinline__ floatx4 mfma16(short8 a, short8 b, floatx4 c) {
    return __builtin_amdgcn_mfma_f32_16x16x32_bf16(a, b, c, 0, 0, 0);
}

// ---------------- Phase A ----------------

// 512 blocks: deterministic partial |W| sums (16 partials per tile)
__global__ __launch_bounds__(256) void k_sumabs(const float* __restrict__ W1,
                                                const float* __restrict__ W2,
                                                float* __restrict__ partials) {
    int blk = blockIdx.x;
    bool isW1 = blk < 256;
    const float* W = (isW1 ? W1 : W2) + (long)(isW1 ? blk : blk - 256) * 4096;
    float s = 0.f;
    #pragma unroll
    for (int i = 0; i < 4; i++) {
        floatx4 v = *(const floatx4*)(W + i * 1024 + threadIdx.x * 4);
        s += fabsf(v[0]) + fabsf(v[1]) + fabsf(v[2]) + fabsf(v[3]);
    }
    __shared__ float red[256];
    red[threadIdx.x] = s; __syncthreads();
    for (int st = 128; st > 0; st >>= 1) {
        if (threadIdx.x < st) red[threadIdx.x] += red[threadIdx.x + st];
        __syncthreads();
    }
    if (threadIdx.x == 0) partials[blk] = red[0];
}

// 128 blocks: W1 quant+transpose via LDS tile (coalesced both sides) + W1 ternsum
__global__ __launch_bounds__(256) void k_quant(
        const float* __restrict__ W1, const float* __restrict__ partials,
        unsigned short* __restrict__ W1qT, float* ternsum) {
    __shared__ unsigned short lt[64 * 136];
    __shared__ float red[256];
    int blk = blockIdx.x;
    int tid = threadIdx.x;
    float dsum = 0.f;

    int t = blk >> 3, n0 = (blk & 7) * 64;
    const float* part = partials + t * 16;
    float ssum = 0.f;
    #pragma unroll
    for (int i = 0; i < 16; i++) ssum += part[i];
    float s = ssum * (1.0f / 65536.0f);
    float thr = 0.7f * s;
    const float* Wt = W1 + (long)t * 65536;
    int j = tid & 63, dbase = tid >> 6;
    #pragma unroll 4
    for (int i = 0; i < 32; i++) {
        int d = i * 4 + dbase;
        float w = Wt[d * 512 + n0 + j];
        float q = (fabsf(w) > thr) ? (w > 0.f ? s : -s) : 0.f;
        dsum += fabsf(w - q);
        lt[j * 136 + d] = f2bf(q);
    }
    __syncthreads();
    int n = tid >> 2, qd = (tid & 3) * 32;
    unsigned short* dst = W1qT + (long)t * 65536 + (n0 + n) * 128 + qd;
    const unsigned short* srcr = lt + n * 136 + qd;
    #pragma unroll
    for (int p = 0; p < 4; p++)
        *(uintx4*)(dst + p * 8) = *(const uintx4*)(srcr + p * 8);

    red[tid] = dsum; __syncthreads();
    for (int st2 = 128; st2 > 0; st2 >>= 1) {
        if (tid < st2) red[tid] += red[tid + st2];
        __syncthreads();
    }
    if (tid == 0) atomicAdd(ternsum, red[0]);
}

// fused tables: blocks 0..292 = base tables + Wh1T; blocks 293..325 = router tables
__global__ void k_tablesF(const float* __restrict__ op_embed, const float* __restrict__ W_in,
                          const float* __restrict__ b_in, const float* __restrict__ Wh1,
                          const float* __restrict__ Wr,
                          float* embW, float* Ta, float* Tb, float* Tc,
                          unsigned short* Wh1T,
                          float* embWr, float* TaR, float* TbR, float* TcR) {
    if (blockIdx.x < 293) {
        int i = blockIdx.x * 256 + threadIdx.x;
        if (i < 1024) {
            int op = i >> 7, j = i & 127;
            float s = b_in[j];
            #pragma unroll
            for (int k = 0; k < 32; k++) s += op_embed[op * 32 + k] * W_in[k * 128 + j];
            embW[i] = s;
        } else if (i < 1024 + 32768) {
            int r = i - 1024; int a = r >> 7, j = r & 127;
            float s = 0.f;
            #pragma unroll
            for (int bit = 0; bit < 8; bit++) if ((a >> bit) & 1) s += W_in[(32 + bit) * 128 + j];
            Ta[r] = s;
        } else if (i < 33792 + 32768) {
            int r = i - 33792; int b = r >> 7, j = r & 127;
            float s = 0.f;
            #pragma unroll
            for (int bit = 0; bit < 8; bit++) if ((b >> bit) & 1) s += W_in[(40 + bit) * 128 + j];
            Tb[r] = s;
        } else if (i < 66560 + 128) {
            int j = i - 66560; Tc[j] = W_in[48 * 128 + j];
        } else if (i < 66688 + 8192) {
            int r = i - 66688; int h = r >> 7, k = r & 127;
            Wh1T[r] = f2bf(Wh1[k * 64 + h]);
        }
    } else {
        int jdx = (blockIdx.x - 293) * 256 + threadIdx.x;
        if (jdx < 4096) {            // TaR[a][t]
            int a = jdx >> 4, t = jdx & 15;
            float s = 0.f;
            for (int j = 0; j < 128; j++) {
                float ta = 0.f;
                #pragma unroll
                for (int bit = 0; bit < 8; bit++)
                    if ((a >> bit) & 1) ta += W_in[(32 + bit) * 128 + j];
                s += ta * Wr[j * 16 + t];
            }
            TaR[jdx] = s;
        } else if (jdx < 8192) {     // TbR[b][t]
            int r = jdx - 4096; int b = r >> 4, t = r & 15;
            float s = 0.f;
            for (int j = 0; j < 128; j++) {
                float tb = 0.f;
                #pragma unroll
                for (int bit = 0; bit < 8; bit++)
                    if ((b >> bit) & 1) tb += W_in[(40 + bit) * 128 + j];
                s += tb * Wr[j * 16 + t];
            }
            TbR[r] = s;
        } else if (jdx < 8320) {     // embWr[op][t]
            int e = jdx - 8192; int op = e >> 4, t = e & 15;
            float s = 0.f;
            for (int j = 0; j < 128; j++) {
                float ej = b_in[j];
                #pragma unroll
                for (int k = 0; k < 32; k++) ej += op_embed[op * 32 + k] * W_in[k * 128 + j];
                s += ej * Wr[j * 16 + t];
            }
            embWr[e] = s;
        } else if (jdx < 8336) {     // TcR[t]
            int t = jdx - 8320;
            float s = 0.f;
            for (int j = 0; j < 128; j++) s += W_in[48 * 128 + j] * Wr[j * 16 + t];
            TcR[t] = s;
        }
    }
}

// W23qT[t][h][n] = (W2q[t] @ Wh1)^T; W2 quantized on the fly (also W2 ternsum)
__global__ __launch_bounds__(256) void k_w23(
        const float* __restrict__ W2, const float* __restrict__ partials,
        const unsigned short* __restrict__ Wh1T,
        unsigned short* __restrict__ W23qT, float* ternsum) {
    __shared__ float red[256];
    int t = blockIdx.x >> 3, n0 = (blockIdx.x & 7) * 64;
    int tid = threadIdx.x;
    int lane = tid & 63, w = tid >> 6;
    int lane15 = lane & 15, lgrp = lane >> 4;

    const float* part = partials + 256 + t * 16;
    float ssum = 0.f;
    #pragma unroll
    for (int i = 0; i < 16; i++) ssum += part[i];
    float s = ssum * (1.0f / 65536.0f);
    float thr = 0.7f * s;

    int n = n0 + w * 16 + lane15;
    const float* w2row = W2 + (long)t * 65536 + n * 128 + lgrp * 8;
    float dsum = 0.f;
    short8 bfr[4];
    #pragma unroll
    for (int kk = 0; kk < 4; kk++) {
        floatx4 v0 = *(const floatx4*)(w2row + kk * 32);
        floatx4 v1 = *(const floatx4*)(w2row + kk * 32 + 4);
        float q[8];
        #pragma unroll
        for (int r = 0; r < 4; r++) {
            q[r]     = (fabsf(v0[r]) > thr) ? (v0[r] > 0.f ? s : -s) : 0.f;
            q[r + 4] = (fabsf(v1[r]) > thr) ? (v1[r] > 0.f ? s : -s) : 0.f;
            dsum += fabsf(v0[r] - q[r]) + fabsf(v1[r] - q[r + 4]);
        }
        uintx4 o;
        o[0] = pk2bf(q[0], q[1]); o[1] = pk2bf(q[2], q[3]);
        o[2] = pk2bf(q[4], q[5]); o[3] = pk2bf(q[6], q[7]);
        bfr[kk] = __builtin_bit_cast(short8, o);
    }

    floatx4 acc[4];
    #pragma unroll
    for (int i = 0; i < 4; i++) acc[i] = (floatx4){0.f, 0.f, 0.f, 0.f};
    #pragma unroll
    for (int kk = 0; kk < 4; kk++) {
        #pragma unroll
        for (int ht = 0; ht < 4; ht++) {
            short8 af = *(const short8*)(Wh1T + (ht * 16 + lane15) * 128 + lgrp * 8 + kk * 32);
            acc[ht] = mfma16(af, bfr[kk], acc[ht]);
        }
    }
    #pragma unroll
    for (int ht = 0; ht < 4; ht++) {
        #pragma unroll
        for (int r = 0; r < 4; r++) {
            int h = ht * 16 + lgrp * 4 + r;
            W23qT[((long)t * 64 + h) * 512 + n] = f2bf(acc[ht][r]);
        }
    }

    red[tid] = dsum; __syncthreads();
    for (int st2 = 128; st2 > 0; st2 >>= 1) {
        if (tid < st2) red[tid] += red[tid + st2];
        __syncthreads();
    }
    if (tid == 0) atomicAdd(ternsum, red[0]);
}

// ---------------- Phase B: router + x (proven round-5/6 version) ----------------

__global__ __launch_bounds__(256) void k_front(
        const int* __restrict__ op_idx, const int* __restrict__ a_in,
        const int* __restrict__ b_in_i, const int* __restrict__ c_in,
        const float* __restrict__ embW, const float* __restrict__ Ta,
        const float* __restrict__ Tb, const float* __restrict__ Tc,
        const float* __restrict__ embWr, const float* __restrict__ TaR,
        const float* __restrict__ TbR, const float* __restrict__ TcR,
        unsigned short* __restrict__ xq, float* __restrict__ gate_out,
        float* psum, int* cnt, float* __restrict__ d_idx) {
    __shared__ float sp[4][16];
    __shared__ int sc[4][16];
    int gid = blockIdx.x * 256 + threadIdx.x;
    int lane = threadIdx.x & 63;
    int j = lane & 15;
    int grpbase = lane & 48;
    float psum_acc = 0.f; int cnt_acc = 0;

    #pragma unroll 1
    for (int it = 0; it < 16; it++) {
        int tok = it * 16384 + (gid >> 4);
        int op = op_idx[tok], a = a_in[tok], b = b_in_i[tok], c = c_in[tok];
        float cf = (float)c;

        float lg = embWr[op * 16 + j] + TaR[a * 16 + j] + TbR[b * 16 + j] + cf * TcR[j];
        float m = lg;
        m = fmaxf(m, __shfl_xor(m, 8, 16));
        m = fmaxf(m, __shfl_xor(m, 4, 16));
        m = fmaxf(m, __shfl_xor(m, 2, 16));
        m = fmaxf(m, __shfl_xor(m, 1, 16));
        float p = __expf(lg - m);
        float sm = p;
        sm += __shfl_xor(sm, 8, 16);
        sm += __shfl_xor(sm, 4, 16);
        sm += __shfl_xor(sm, 2, 16);
        sm += __shfl_xor(sm, 1, 16);
        float g = __builtin_amdgcn_rcpf(sm);
        unsigned long long ball = __ballot(lg == m);
        int bi = __ffsll((unsigned long long)((ball >> grpbase) & 0xffffULL)) - 1;
        psum_acc += p * g;
        cnt_acc += (j == bi) ? 1 : 0;
        if (j == 0) { gate_out[tok] = g; d_idx[tok] = (float)bi; }

        int d0 = j * 8;
        const floatx4* E  = (const floatx4*)(embW + op * 128 + d0);
        const floatx4* A4 = (const floatx4*)(Ta + a * 128 + d0);
        const floatx4* B4 = (const floatx4*)(Tb + b * 128 + d0);
        const floatx4* C4 = (const floatx4*)(Tc + d0);
        floatx4 v0 = E[0] + A4[0] + B4[0] + cf * C4[0];
        floatx4 v1 = E[1] + A4[1] + B4[1] + cf * C4[1];
        uintx4 o;
        o[0] = pk2bf(v0[0], v0[1]);
        o[1] = pk2bf(v0[2], v0[3]);
        o[2] = pk2bf(v1[0], v1[1]);
        o[3] = pk2bf(v1[2], v1[3]);
        *(uintx4*)(xq + (long)tok * 128 + d0) = o;
    }

    psum_acc += __shfl_xor(psum_acc, 16);
    psum_acc += __shfl_xor(psum_acc, 32);
    cnt_acc += __shfl_xor(cnt_acc, 16);
    cnt_acc += __shfl_xor(cnt_acc, 32);
    int wv = threadIdx.x >> 6;
    if (lane < 16) { sp[wv][j] = psum_acc; sc[wv][j] = cnt_acc; }
    __syncthreads();
    if (threadIdx.x < 16) {
        int jj = threadIdx.x;
        atomicAdd(&psum[jj], sp[0][jj] + sp[1][jj] + sp[2][jj] + sp[3][jj]);
        atomicAdd(&cnt[jj], sc[0][jj] + sc[1][jj] + sc[2][jj] + sc[3][jj]);
    }
}

// ---------------- scatter: packed {tok, gate} records at EXACT dense offsets ----------------

__global__ void k_scatter(const float* __restrict__ d_idx, const float* __restrict__ gate,
                          const int* __restrict__ cnt,
                          int* fill, uintx2* __restrict__ records) {
    __shared__ int lc[16], lbase[16];
    if (threadIdx.x < 16) lc[threadIdx.x] = 0;
    __syncthreads();
    int offs[16];
    {
        int off = 0;
        #pragma unroll
        for (int tt = 0; tt < 16; tt++) { offs[tt] = off; off += cnt[tt]; }
    }
    int tok = blockIdx.x * 256 + threadIdx.x;
    int t = (int)d_idx[tok];
    int lpos = atomicAdd(&lc[t], 1);
    __syncthreads();
    if (threadIdx.x < 16) lbase[threadIdx.x] = atomicAdd(&fill[threadIdx.x], lc[threadIdx.x]);
    __syncthreads();
    uintx2 rec;
    rec[0] = (unsigned)tok;
    rec[1] = __float_as_uint(gate[tok]);
    records[offs[t] + lbase[t] + lpos] = rec;
}

// ---------------- Phase C: MoE FFN + fused head ----------------
// Round-5 structure (2 LDS buffers) + W23 register prefetch.

__global__ __launch_bounds__(256, 4) void k_ffn(
    const unsigned short* __restrict__ xq, const uintx2* __restrict__ recs,
    const int* __restrict__ cnt_g,
    const float* __restrict__ psum_g, const float* __restrict__ ternsum_g,
    const unsigned short* __restrict__ W1qT, const unsigned short* __restrict__ W23qT,
    const float* __restrict__ Wh2, const float* __restrict__ bh1,
    const float* __restrict__ bh2,
    float* __restrict__ result, float* __restrict__ d_aux) {

    extern __shared__ __align__(16) unsigned char smem[];
    unsigned short* Ax = (unsigned short*)smem;            // [64][136] bf16
    unsigned short* Pb = Ax + 64 * 136;                    // [64][136] bf16; later H f32 [64][68]
    int*   toks = (int*)(smem + 34816);
    float* gats = (float*)(smem + 35072);
    float* Wh2l = (float*)(smem + 35328);                  // 512 f
    float* bh2l = (float*)(smem + 37376);                  // 8 f
    float* bh1l = (float*)(smem + 37408);                  // 64 f

    int bid = blockIdx.x;
    int t = -1, ci = 0, nt = 0, base = 0;
    {
        int coff = 0, off = 0;
        #pragma unroll 1
        for (int tt = 0; tt < 16; tt++) {
            int c = cnt_g[tt];
            int ch = (c + 63) >> 6;
            if (t < 0 && bid < coff + ch) { t = tt; ci = bid - coff; nt = c; base = off + ci * 64; }
            coff += ch; off += c;
        }
    }
    if (t < 0) return;
    int nvalid = nt - ci * 64; if (nvalid > 64) nvalid = 64;

    int tid = threadIdx.x;
    if (tid < 64) {
        uintx2 rec = {0xFFFFFFFFu, 0u};
        if (tid < nvalid) rec = recs[base + tid];
        toks[tid] = (int)rec[0];
        gats[tid] = __uint_as_float(rec[1]);
    }
    Wh2l[tid] = Wh2[tid];
    Wh2l[tid + 256] = Wh2[tid + 256];
    if (tid < 8) bh2l[tid] = bh2[tid];
    else if (tid < 72) bh1l[tid - 8] = bh1[tid - 8];
    __syncthreads();

    // stage x rows (gathered, zero-padded)
    #pragma unroll
    for (int it = 0; it < 4; it++) {
        int seg = it * 256 + tid; int r = seg >> 4, sg = seg & 15;
        int tk = toks[r];
        uintx4 v = {0u, 0u, 0u, 0u};
        if (tk >= 0) v = *(const uintx4*)(xq + (long)tk * 128 + sg * 8);
        *(uintx4*)(Ax + r * 136 + sg * 8) = v;
    }
    __syncthreads();

    int lane = tid & 63, dh = tid >> 6;
    int lane15 = lane & 15, lgrp = lane >> 4;

    floatx4 acc3[4];
    #pragma unroll
    for (int jj = 0; jj < 4; jj++) acc3[jj] = (floatx4){0.f, 0.f, 0.f, 0.f};

    const unsigned short* w1p = W1qT + (long)t * 65536 + lgrp * 8;
    const unsigned short* w23p = W23qT + ((long)t * 64 + dh * 16 + lane15) * 512 + lgrp * 8;

    for (int nc = 0; nc < 4; nc++) {
        // prefetch W23 A-fragments for this chunk's GEMM2'
        const unsigned short* w23c = w23p + nc * 128;
        short8 af23[4];
        #pragma unroll
        for (int kk = 0; kk < 4; kk++) af23[kk] = *(const short8*)(w23c + kk * 32);

        // GEMM1: A = W1 rows (global), B = Ax (LDS)
        floatx4 acc1[2][4];
        #pragma unroll
        for (int i = 0; i < 2; i++)
            #pragma unroll
            for (int jj = 0; jj < 4; jj++) acc1[i][jj] = (floatx4){0.f, 0.f, 0.f, 0.f};

        const unsigned short* w1c = w1p + (long)nc * 16384 + (dh * 32 + lane15) * 128;
        #pragma unroll
        for (int kk = 0; kk < 4; kk++) {
            short8 af0 = *(const short8*)(w1c + kk * 32);
            short8 af1 = *(const short8*)(w1c + 2048 + kk * 32);
            int ko = kk * 32 + lgrp * 8;
            #pragma unroll
            for (int mt = 0; mt < 4; mt++) {
                short8 bf = *(const short8*)(Ax + (mt * 16 + lane15) * 136 + ko);
                acc1[0][mt] = mfma16(af0, bf, acc1[0][mt]);
                acc1[1][mt] = mfma16(af1, bf, acc1[1][mt]);
            }
        }
        __syncthreads();                     // prev GEMM2' Pb reads done

        // gelu -> Pb[m][k2local]
        #pragma unroll
        for (int i = 0; i < 2; i++) {
            int k2b = dh * 32 + i * 16 + lgrp * 4;
            #pragma unroll
            for (int mt = 0; mt < 4; mt++) {
                int m = mt * 16 + lane15;
                floatx4 v = acc1[i][mt];
                float g0 = gelu_f(v[0]), g1v = gelu_f(v[1]);
                float g2v = gelu_f(v[2]), g3 = gelu_f(v[3]);
                uintx2 o; o[0] = pk2bf(g0, g1v); o[1] = pk2bf(g2v, g3);
                *(uintx2*)(Pb + m * 136 + k2b) = o;
            }
        }
        __syncthreads();                     // Pb ready

        // GEMM2': A = prefetched W23 frags, B = Pb (LDS), accumulate
        #pragma unroll
        for (int kk = 0; kk < 4; kk++) {
            int ko = kk * 32 + lgrp * 8;
            #pragma unroll
            for (int mt = 0; mt < 4; mt++) {
                short8 bf = *(const short8*)(Pb + (mt * 16 + lane15) * 136 + ko);
                acc3[mt] = mfma16(af23[kk], bf, acc3[mt]);
            }
        }
    }

    __syncthreads();                         // all GEMM2' reads done
    float* H = (float*)Pb;                   // [64 m][68] f32
    int hb = dh * 16 + lgrp * 4;
    floatx4 b4 = *(const floatx4*)(bh1l + hb);
    #pragma unroll
    for (int mt = 0; mt < 4; mt++) {
        int m = mt * 16 + lane15;
        float gm = gats[m];
        floatx4 v;
        v[0] = fmaxf(acc3[mt][0] * gm + b4[0], 0.f);
        v[1] = fmaxf(acc3[mt][1] * gm + b4[1], 0.f);
        v[2] = fmaxf(acc3[mt][2] * gm + b4[2], 0.f);
        v[3] = fmaxf(acc3[mt][3] * gm + b4[3], 0.f);
        *(floatx4*)(H + m * 68 + hb) = v;
    }
    __syncthreads();                         // H complete

    int mloc = tid >> 2, c0 = (tid & 3) * 2;
    int tk = toks[mloc];
    float z0 = bh2l[c0], z1 = bh2l[c0 + 1];
    const floatx4* Hr4 = (const floatx4*)(H + mloc * 68);
    #pragma unroll
    for (int h4 = 0; h4 < 16; h4++) {
        floatx4 hv = Hr4[h4];
        #pragma unroll
        for (int r = 0; r < 4; r++) {
            int h = h4 * 4 + r;
            z0 += hv[r] * Wh2l[h * 8 + c0];
            z1 += hv[r] * Wh2l[h * 8 + c0 + 1];
        }
    }
    if (tk >= 0) {
        float2 rr;
        rr.x = __builtin_amdgcn_rcpf(1.0f + __expf(-z0));
        rr.y = __builtin_amdgcn_rcpf(1.0f + __expf(-z1));
        *(float2*)(result + (long)tk * 8 + c0) = rr;
    }

    // aux loss (block 0 only)
    if (bid == 0 && tid == 0) {
        const float Bf = 262144.0f;
        float tern = ternsum_g[0] * (1.0f / 1048576.0f);
        float sp = 0.f; float cp[4] = {0.f, 0.f, 0.f, 0.f};
        for (int tt = 0; tt < 16; tt++) {
            float frac = (float)cnt_g[tt] / Bf, mp = psum_g[tt] / Bf;
            sp += frac * mp; cp[tt >> 2] += mp;
        }
        float dv = 0.f;
        for (int cc = 0; cc < 4; cc++) dv += cp[cc] * logf(cp[cc] + 1e-9f);
        d_aux[0] = 0.01f * tern + 0.005f * (16.0f * sp) + 0.01f * dv;
    }
}

// ---------------- launch ----------------

extern "C" void kernel_launch(void* const* d_in, const int* in_sizes, int n_in,
                              void* d_out, int out_size, void* d_ws, size_t ws_size,
                              hipStream_t stream) {
    const int* op_idx = (const int*)d_in[0];
    const int* a_in   = (const int*)d_in[1];
    const int* b_in_i = (const int*)d_in[2];
    const int* c_in   = (const int*)d_in[3];
    const float* op_embed = (const float*)d_in[4];
    const float* W_in  = (const float*)d_in[5];
    const float* b_in  = (const float*)d_in[6];
    const float* Wr    = (const float*)d_in[7];
    const float* W1    = (const float*)d_in[8];
    const float* W2    = (const float*)d_in[9];
    const float* Wh1   = (const float*)d_in[10];
    const float* bh1   = (const float*)d_in[11];
    const float* Wh2   = (const float*)d_in[12];
    const float* bh2   = (const float*)d_in[13];

    const long B = in_sizes[0];  // 262144
    float* result = (float*)d_out;
    float* d_idx  = (float*)d_out + B * 8;
    float* d_aux  = (float*)d_out + B * 9;

    unsigned char* ws = (unsigned char*)d_ws;
    unsigned short* xq    = (unsigned short*)(ws + 0);            // 64 MB
    unsigned short* W1qT  = (unsigned short*)(ws + 67108864);     // 2 MB
    unsigned short* W23qT = (unsigned short*)(ws + 69206016);     // 1 MB
    unsigned short* Wh1T  = (unsigned short*)(ws + 70254592);     // 16 KB
    float* gate   = (float*)(ws + 70270976);                      // 1 MB
    uintx2* records = (uintx2*)(ws + 71319552);                   // 2 MB (dense)
    float* Ta    = (float*)(ws + 73416704);                       // 128 KB
    float* Tb    = (float*)(ws + 73547776);                       // 128 KB
    float* embW  = (float*)(ws + 73678848);                       // 4 KB
    float* Tc    = (float*)(ws + 73682944);                       // 512 B
    float* TaR   = (float*)(ws + 73683456);                       // 16 KB
    float* TbR   = (float*)(ws + 73699840);                       // 16 KB
    float* embWr = (float*)(ws + 73716224);                       // 512 B
    float* TcR   = (float*)(ws + 73716736);                       // 64 B
    float* partials = (float*)(ws + 73716800);                    // 2 KB
    unsigned char* acc = ws + 73718848;
    float* ternsum = (float*)(acc + 0);
    float* psum    = (float*)(acc + 64);
    int*   cnt     = (int*)(acc + 128);
    int*   fill    = (int*)(acc + 192);

    hipMemsetAsync(acc, 0, 256, stream);

    k_sumabs<<<512, 256, 0, stream>>>(W1, W2, partials);
    k_quant<<<128, 256, 0, stream>>>(W1, partials, W1qT, ternsum);
    k_tablesF<<<326, 256, 0, stream>>>(op_embed, W_in, b_in, Wh1, Wr,
                                       embW, Ta, Tb, Tc, Wh1T,
                                       embWr, TaR, TbR, TcR);
    k_w23<<<128, 256, 0, stream>>>(W2, partials, Wh1T, W23qT, ternsum);
    k_front<<<1024, 256, 0, stream>>>(op_idx, a_in, b_in_i, c_in,
                                      embW, Ta, Tb, Tc, embWr, TaR, TbR, TcR,
                                      xq, gate, psum, cnt, d_idx);
    k_scatter<<<(int)(B / 256), 256, 0, stream>>>(d_idx, gate, cnt, fill, records);
    k_ffn<<<4112, 256, 37664, stream>>>(xq, records, cnt, psum, ternsum,
                                        W1qT, W23qT, Wh2, bh1, bh2, result, d_aux);
}

// Round 9
// 309.172 us; speedup vs baseline: 1.0187x; 1.0187x over previous
//
#include <hip/hip_runtime.h>
#include <hip/hip_bf16.h>
#include <math.h>

typedef __attribute__((ext_vector_type(8))) short short8;
typedef __attribute__((ext_vector_type(4))) float floatx4;
typedef __attribute__((ext_vector_type(4))) unsigned int uintx4;
typedef __attribute__((ext_vector_type(2))) unsigned int uintx2;

__device__ __forceinline__ unsigned short f2bf(float f) {
    unsigned int u = __float_as_uint(f);
    unsigned int r = (u + 0x7fffu + ((u >> 16) & 1u)) >> 16;
    return (unsigned short)r;
}

#if defined(__has_builtin)
#if __has_builtin(__builtin_amdgcn_cvt_pk_bf16_f32)
#define HAVE_PK_BF16 1
#endif
#endif

#ifdef HAVE_PK_BF16
typedef __bf16 bf16x2_t __attribute__((ext_vector_type(2)));
__device__ __forceinline__ unsigned int pk2bf(float a, float b) {
    bf16x2_t v = __builtin_amdgcn_cvt_pk_bf16_f32(a, b);
    return __builtin_bit_cast(unsigned int, v);
}
#else
__device__ __forceinline__ unsigned int pk2bf(float a, float b) {
    unsigned int ua = __float_as_uint(a);
    ua = ua + 0x7fffu + ((ua >> 16) & 1u);
    unsigned int ub = __float_as_uint(b);
    ub = ub + 0x7fffu + ((ub >> 16) & 1u);
    return (ua >> 16) | (ub & 0xffff0000u);
}
#endif

// tanh-gelu via u*sigmoid(y), Schraudolph fast exp
__device__ __forceinline__ float gelu_f(float u) {
    float u2 = u * u;
    float y = u * fmaf(u2, 0.0713548163f, 1.5957691216f);
    y = fminf(fmaxf(y, -87.0f), 87.0f);
    float f = fmaf(y, -12102203.16f, 1064866805.0f);   // bits of e^{-y}
    float e = __int_as_float((int)f);
    return u * __builtin_amdgcn_rcpf(1.0f + e);
}

__device__ __forceinline__ floatx4 mfma16(short8 a, short8 b, floatx4 c) {
    return __builtin_amdgcn_mfma_f32_16x16x32_bf16(a, b, c, 0, 0, 0);
}

// ---------------- Phase A (fused): sumabs (blocks 0-511) + tables (512-837) ----------------

__global__ __launch_bounds__(256) void kA(
        const float* __restrict__ W1, const float* __restrict__ W2,
        const float* __restrict__ op_embed, const float* __restrict__ W_in,
        const float* __restrict__ b_in, const float* __restrict__ Wh1,
        const float* __restrict__ Wr,
        float* __restrict__ partials,
        float* embW, float* Ta, float* Tb, float* Tc, unsigned short* Wh1T,
        float* embWr, float* TaR, float* TbR, float* TcR,
        unsigned int* accz) {
    if (blockIdx.x < 512) {
        int blk = blockIdx.x;
        bool isW1 = blk < 256;
        const float* W = (isW1 ? W1 : W2) + (long)(isW1 ? blk : blk - 256) * 4096;
        float s = 0.f;
        #pragma unroll
        for (int i = 0; i < 4; i++) {
            floatx4 v = *(const floatx4*)(W + i * 1024 + threadIdx.x * 4);
            s += fabsf(v[0]) + fabsf(v[1]) + fabsf(v[2]) + fabsf(v[3]);
        }
        __shared__ float red[256];
        red[threadIdx.x] = s; __syncthreads();
        for (int st = 128; st > 0; st >>= 1) {
            if (threadIdx.x < st) red[threadIdx.x] += red[threadIdx.x + st];
            __syncthreads();
        }
        if (threadIdx.x == 0) partials[blk] = red[0];
        return;
    }
    int bidT = blockIdx.x - 512;
    if (bidT == 0 && threadIdx.x < 64) accz[threadIdx.x] = 0u;  // zero acc region
    if (bidT < 293) {
        int i = bidT * 256 + threadIdx.x;
        if (i < 1024) {
            int op = i >> 7, j = i & 127;
            float s = b_in[j];
            #pragma unroll
            for (int k = 0; k < 32; k++) s += op_embed[op * 32 + k] * W_in[k * 128 + j];
            embW[i] = s;
        } else if (i < 1024 + 32768) {
            int r = i - 1024; int a = r >> 7, j = r & 127;
            float s = 0.f;
            #pragma unroll
            for (int bit = 0; bit < 8; bit++) if ((a >> bit) & 1) s += W_in[(32 + bit) * 128 + j];
            Ta[r] = s;
        } else if (i < 33792 + 32768) {
            int r = i - 33792; int b = r >> 7, j = r & 127;
            float s = 0.f;
            #pragma unroll
            for (int bit = 0; bit < 8; bit++) if ((b >> bit) & 1) s += W_in[(40 + bit) * 128 + j];
            Tb[r] = s;
        } else if (i < 66560 + 128) {
            int j = i - 66560; Tc[j] = W_in[48 * 128 + j];
        } else if (i < 66688 + 8192) {
            int r = i - 66688; int h = r >> 7, k = r & 127;
            Wh1T[r] = f2bf(Wh1[k * 64 + h]);
        }
    } else {
        int jdx = (bidT - 293) * 256 + threadIdx.x;
        if (jdx < 4096) {            // TaR[a][t]
            int a = jdx >> 4, t = jdx & 15;
            float s = 0.f;
            for (int j = 0; j < 128; j++) {
                float ta = 0.f;
                #pragma unroll
                for (int bit = 0; bit < 8; bit++)
                    if ((a >> bit) & 1) ta += W_in[(32 + bit) * 128 + j];
                s += ta * Wr[j * 16 + t];
            }
            TaR[jdx] = s;
        } else if (jdx < 8192) {     // TbR[b][t]
            int r = jdx - 4096; int b = r >> 4, t = r & 15;
            float s = 0.f;
            for (int j = 0; j < 128; j++) {
                float tb = 0.f;
                #pragma unroll
                for (int bit = 0; bit < 8; bit++)
                    if ((b >> bit) & 1) tb += W_in[(40 + bit) * 128 + j];
                s += tb * Wr[j * 16 + t];
            }
            TbR[r] = s;
        } else if (jdx < 8320) {     // embWr[op][t]
            int e = jdx - 8192; int op = e >> 4, t = e & 15;
            float s = 0.f;
            for (int j = 0; j < 128; j++) {
                float ej = b_in[j];
                #pragma unroll
                for (int k = 0; k < 32; k++) ej += op_embed[op * 32 + k] * W_in[k * 128 + j];
                s += ej * Wr[j * 16 + t];
            }
            embWr[e] = s;
        } else if (jdx < 8336) {     // TcR[t]
            int t = jdx - 8320;
            float s = 0.f;
            for (int j = 0; j < 128; j++) s += W_in[48 * 128 + j] * Wr[j * 16 + t];
            TcR[t] = s;
        }
    }
}

// ---------------- Phase A2 (fused): W1 quant+transpose (0-511) + W23 (512-639) ----------------

__global__ __launch_bounds__(256) void kB(
        const float* __restrict__ W1, const float* __restrict__ W2,
        const float* __restrict__ partials, const unsigned short* __restrict__ Wh1T,
        unsigned short* __restrict__ W1qT, unsigned short* __restrict__ W23qT,
        float* ternsum) {
    __shared__ unsigned short lt[64 * 40];
    __shared__ float red[256];
    int tid = threadIdx.x;
    float dsum = 0.f;

    if (blockIdx.x < 512) {
        // W1 quant+transpose: 16 t x 8 n0 x 4 dq; reads coalesced 256B rows,
        // LDS transpose tile (stride 40 shorts = 80B, 16B-aligned), b128 writes.
        int bid = blockIdx.x;
        int t = bid >> 5, sub = bid & 31;
        int n0 = (sub >> 2) * 64, dq = sub & 3;
        const float* part = partials + t * 16;
        float ssum = 0.f;
        #pragma unroll
        for (int i = 0; i < 16; i++) ssum += part[i];
        float s = ssum * (1.0f / 65536.0f);
        float thr = 0.7f * s;
        const float* Wt = W1 + (long)t * 65536 + (long)dq * 32 * 512;
        int j = tid & 63, d4 = tid >> 6;
        #pragma unroll
        for (int it = 0; it < 8; it++) {
            int d = it * 4 + d4;
            float w = Wt[d * 512 + n0 + j];
            float q = (fabsf(w) > thr) ? (w > 0.f ? s : -s) : 0.f;
            dsum += fabsf(w - q);
            lt[j * 40 + d] = f2bf(q);
        }
        __syncthreads();
        int n = tid >> 2, ds = (tid & 3) * 8;
        *(uintx4*)(W1qT + (long)t * 65536 + (n0 + n) * 128 + dq * 32 + ds) =
            *(const uintx4*)(lt + n * 40 + ds);
    } else {
        // W23qT[t][h][n] = (W2q[t] @ Wh1)^T; W2 quantized on the fly
        int bid = blockIdx.x - 512;
        int t = bid >> 3, n0 = (bid & 7) * 64;
        int lane = tid & 63, w = tid >> 6;
        int lane15 = lane & 15, lgrp = lane >> 4;

        const float* part = partials + 256 + t * 16;
        float ssum = 0.f;
        #pragma unroll
        for (int i = 0; i < 16; i++) ssum += part[i];
        float s = ssum * (1.0f / 65536.0f);
        float thr = 0.7f * s;

        int n = n0 + w * 16 + lane15;
        const float* w2row = W2 + (long)t * 65536 + n * 128 + lgrp * 8;
        short8 bfr[4];
        #pragma unroll
        for (int kk = 0; kk < 4; kk++) {
            floatx4 v0 = *(const floatx4*)(w2row + kk * 32);
            floatx4 v1 = *(const floatx4*)(w2row + kk * 32 + 4);
            float q[8];
            #pragma unroll
            for (int r = 0; r < 4; r++) {
                q[r]     = (fabsf(v0[r]) > thr) ? (v0[r] > 0.f ? s : -s) : 0.f;
                q[r + 4] = (fabsf(v1[r]) > thr) ? (v1[r] > 0.f ? s : -s) : 0.f;
                dsum += fabsf(v0[r] - q[r]) + fabsf(v1[r] - q[r + 4]);
            }
            uintx4 o;
            o[0] = pk2bf(q[0], q[1]); o[1] = pk2bf(q[2], q[3]);
            o[2] = pk2bf(q[4], q[5]); o[3] = pk2bf(q[6], q[7]);
            bfr[kk] = __builtin_bit_cast(short8, o);
        }

        floatx4 acc[4];
        #pragma unroll
        for (int i = 0; i < 4; i++) acc[i] = (floatx4){0.f, 0.f, 0.f, 0.f};
        #pragma unroll
        for (int kk = 0; kk < 4; kk++) {
            #pragma unroll
            for (int ht = 0; ht < 4; ht++) {
                short8 af = *(const short8*)(Wh1T + (ht * 16 + lane15) * 128 + lgrp * 8 + kk * 32);
                acc[ht] = mfma16(af, bfr[kk], acc[ht]);
            }
        }
        #pragma unroll
        for (int ht = 0; ht < 4; ht++) {
            #pragma unroll
            for (int r = 0; r < 4; r++) {
                int h = ht * 16 + lgrp * 4 + r;
                W23qT[((long)t * 64 + h) * 512 + n] = f2bf(acc[ht][r]);
            }
        }
    }

    red[tid] = dsum; __syncthreads();
    for (int st2 = 128; st2 > 0; st2 >>= 1) {
        if (tid < st2) red[tid] += red[tid + st2];
        __syncthreads();
    }
    if (tid == 0) atomicAdd(ternsum, red[0]);
}

// ---------------- Phase B: router + x ----------------

__global__ __launch_bounds__(256) void k_front(
        const int* __restrict__ op_idx, const int* __restrict__ a_in,
        const int* __restrict__ b_in_i, const int* __restrict__ c_in,
        const float* __restrict__ embW, const float* __restrict__ Ta,
        const float* __restrict__ Tb, const float* __restrict__ Tc,
        const float* __restrict__ embWr, const float* __restrict__ TaR,
        const float* __restrict__ TbR, const float* __restrict__ TcR,
        unsigned short* __restrict__ xq, float* __restrict__ gate_out,
        float* psum, int* cnt, float* __restrict__ d_idx) {
    __shared__ float sp[4][16];
    __shared__ int sc[4][16];
    int gid = blockIdx.x * 256 + threadIdx.x;
    int lane = threadIdx.x & 63;
    int j = lane & 15;
    int grpbase = lane & 48;
    float psum_acc = 0.f; int cnt_acc = 0;

    #pragma unroll 1
    for (int it = 0; it < 16; it++) {
        int tok = it * 16384 + (gid >> 4);
        int op = op_idx[tok], a = a_in[tok], b = b_in_i[tok], c = c_in[tok];
        float cf = (float)c;

        float lg = embWr[op * 16 + j] + TaR[a * 16 + j] + TbR[b * 16 + j] + cf * TcR[j];
        float m = lg;
        m = fmaxf(m, __shfl_xor(m, 8, 16));
        m = fmaxf(m, __shfl_xor(m, 4, 16));
        m = fmaxf(m, __shfl_xor(m, 2, 16));
        m = fmaxf(m, __shfl_xor(m, 1, 16));
        float p = __expf(lg - m);
        float sm = p;
        sm += __shfl_xor(sm, 8, 16);
        sm += __shfl_xor(sm, 4, 16);
        sm += __shfl_xor(sm, 2, 16);
        sm += __shfl_xor(sm, 1, 16);
        float g = __builtin_amdgcn_rcpf(sm);
        unsigned long long ball = __ballot(lg == m);
        int bi = __ffsll((unsigned long long)((ball >> grpbase) & 0xffffULL)) - 1;
        psum_acc += p * g;
        cnt_acc += (j == bi) ? 1 : 0;
        if (j == 0) { gate_out[tok] = g; d_idx[tok] = (float)bi; }

        int d0 = j * 8;
        const floatx4* E  = (const floatx4*)(embW + op * 128 + d0);
        const floatx4* A4 = (const floatx4*)(Ta + a * 128 + d0);
        const floatx4* B4 = (const floatx4*)(Tb + b * 128 + d0);
        const floatx4* C4 = (const floatx4*)(Tc + d0);
        floatx4 v0 = E[0] + A4[0] + B4[0] + cf * C4[0];
        floatx4 v1 = E[1] + A4[1] + B4[1] + cf * C4[1];
        uintx4 o;
        o[0] = pk2bf(v0[0], v0[1]);
        o[1] = pk2bf(v0[2], v0[3]);
        o[2] = pk2bf(v1[0], v1[1]);
        o[3] = pk2bf(v1[2], v1[3]);
        *(uintx4*)(xq + (long)tok * 128 + d0) = o;
    }

    psum_acc += __shfl_xor(psum_acc, 16);
    psum_acc += __shfl_xor(psum_acc, 32);
    cnt_acc += __shfl_xor(cnt_acc, 16);
    cnt_acc += __shfl_xor(cnt_acc, 32);
    int wv = threadIdx.x >> 6;
    if (lane < 16) { sp[wv][j] = psum_acc; sc[wv][j] = cnt_acc; }
    __syncthreads();
    if (threadIdx.x < 16) {
        int jj = threadIdx.x;
        atomicAdd(&psum[jj], sp[0][jj] + sp[1][jj] + sp[2][jj] + sp[3][jj]);
        atomicAdd(&cnt[jj], sc[0][jj] + sc[1][jj] + sc[2][jj] + sc[3][jj]);
    }
}

// ---------------- scatter: packed {tok, gate} records at EXACT dense offsets ----------------

__global__ void k_scatter(const float* __restrict__ d_idx, const float* __restrict__ gate,
                          const int* __restrict__ cnt,
                          int* fill, uintx2* __restrict__ records) {
    __shared__ int lc[16], lbase[16];
    if (threadIdx.x < 16) lc[threadIdx.x] = 0;
    __syncthreads();
    int offs[16];
    {
        int off = 0;
        #pragma unroll
        for (int tt = 0; tt < 16; tt++) { offs[tt] = off; off += cnt[tt]; }
    }
    int tok = blockIdx.x * 256 + threadIdx.x;
    int t = (int)d_idx[tok];
    int lpos = atomicAdd(&lc[t], 1);
    __syncthreads();
    if (threadIdx.x < 16) lbase[threadIdx.x] = atomicAdd(&fill[threadIdx.x], lc[threadIdx.x]);
    __syncthreads();
    uintx2 rec;
    rec[0] = (unsigned)tok;
    rec[1] = __float_as_uint(gate[tok]);
    records[offs[t] + lbase[t] + lpos] = rec;
}

// ---------------- Phase C: MoE FFN + fused head (unchanged from round 8) ----------------

__global__ __launch_bounds__(256, 4) void k_ffn(
    const unsigned short* __restrict__ xq, const uintx2* __restrict__ recs,
    const int* __restrict__ cnt_g,
    const float* __restrict__ psum_g, const float* __restrict__ ternsum_g,
    const unsigned short* __restrict__ W1qT, const unsigned short* __restrict__ W23qT,
    const float* __restrict__ Wh2, const float* __restrict__ bh1,
    const float* __restrict__ bh2,
    float* __restrict__ result, float* __restrict__ d_aux) {

    extern __shared__ __align__(16) unsigned char smem[];
    unsigned short* Ax = (unsigned short*)smem;            // [64][136] bf16
    unsigned short* Pb = Ax + 64 * 136;                    // [64][136] bf16; later H f32 [64][68]
    int*   toks = (int*)(smem + 34816);
    float* gats = (float*)(smem + 35072);
    float* Wh2l = (float*)(smem + 35328);                  // 512 f
    float* bh2l = (float*)(smem + 37376);                  // 8 f
    float* bh1l = (float*)(smem + 37408);                  // 64 f

    int bid = blockIdx.x;
    int t = -1, ci = 0, nt = 0, base = 0;
    {
        int coff = 0, off = 0;
        #pragma unroll 1
        for (int tt = 0; tt < 16; tt++) {
            int c = cnt_g[tt];
            int ch = (c + 63) >> 6;
            if (t < 0 && bid < coff + ch) { t = tt; ci = bid - coff; nt = c; base = off + ci * 64; }
            coff += ch; off += c;
        }
    }
    if (t < 0) return;
    int nvalid = nt - ci * 64; if (nvalid > 64) nvalid = 64;

    int tid = threadIdx.x;
    if (tid < 64) {
        uintx2 rec = {0xFFFFFFFFu, 0u};
        if (tid < nvalid) rec = recs[base + tid];
        toks[tid] = (int)rec[0];
        gats[tid] = __uint_as_float(rec[1]);
    }
    Wh2l[tid] = Wh2[tid];
    Wh2l[tid + 256] = Wh2[tid + 256];
    if (tid < 8) bh2l[tid] = bh2[tid];
    else if (tid < 72) bh1l[tid - 8] = bh1[tid - 8];
    __syncthreads();

    // stage x rows (gathered, zero-padded)
    #pragma unroll
    for (int it = 0; it < 4; it++) {
        int seg = it * 256 + tid; int r = seg >> 4, sg = seg & 15;
        int tk = toks[r];
        uintx4 v = {0u, 0u, 0u, 0u};
        if (tk >= 0) v = *(const uintx4*)(xq + (long)tk * 128 + sg * 8);
        *(uintx4*)(Ax + r * 136 + sg * 8) = v;
    }
    __syncthreads();

    int lane = tid & 63, dh = tid >> 6;
    int lane15 = lane & 15, lgrp = lane >> 4;

    floatx4 acc3[4];
    #pragma unroll
    for (int jj = 0; jj < 4; jj++) acc3[jj] = (floatx4){0.f, 0.f, 0.f, 0.f};

    const unsigned short* w1p = W1qT + (long)t * 65536 + lgrp * 8;
    const unsigned short* w23p = W23qT + ((long)t * 64 + dh * 16 + lane15) * 512 + lgrp * 8;

    for (int nc = 0; nc < 4; nc++) {
        const unsigned short* w23c = w23p + nc * 128;
        short8 af23[4];
        #pragma unroll
        for (int kk = 0; kk < 4; kk++) af23[kk] = *(const short8*)(w23c + kk * 32);

        floatx4 acc1[2][4];
        #pragma unroll
        for (int i = 0; i < 2; i++)
            #pragma unroll
            for (int jj = 0; jj < 4; jj++) acc1[i][jj] = (floatx4){0.f, 0.f, 0.f, 0.f};

        const unsigned short* w1c = w1p + (long)nc * 16384 + (dh * 32 + lane15) * 128;
        #pragma unroll
        for (int kk = 0; kk < 4; kk++) {
            short8 af0 = *(const short8*)(w1c + kk * 32);
            short8 af1 = *(const short8*)(w1c + 2048 + kk * 32);
            int ko = kk * 32 + lgrp * 8;
            #pragma unroll
            for (int mt = 0; mt < 4; mt++) {
                short8 bf = *(const short8*)(Ax + (mt * 16 + lane15) * 136 + ko);
                acc1[0][mt] = mfma16(af0, bf, acc1[0][mt]);
                acc1[1][mt] = mfma16(af1, bf, acc1[1][mt]);
            }
        }
        __syncthreads();                     // prev GEMM2' Pb reads done

        #pragma unroll
        for (int i = 0; i < 2; i++) {
            int k2b = dh * 32 + i * 16 + lgrp * 4;
            #pragma unroll
            for (int mt = 0; mt < 4; mt++) {
                int m = mt * 16 + lane15;
                floatx4 v = acc1[i][mt];
                float g0 = gelu_f(v[0]), g1v = gelu_f(v[1]);
                float g2v = gelu_f(v[2]), g3 = gelu_f(v[3]);
                uintx2 o; o[0] = pk2bf(g0, g1v); o[1] = pk2bf(g2v, g3);
                *(uintx2*)(Pb + m * 136 + k2b) = o;
            }
        }
        __syncthreads();                     // Pb ready

        #pragma unroll
        for (int kk = 0; kk < 4; kk++) {
            int ko = kk * 32 + lgrp * 8;
            #pragma unroll
            for (int mt = 0; mt < 4; mt++) {
                short8 bf = *(const short8*)(Pb + (mt * 16 + lane15) * 136 + ko);
                acc3[mt] = mfma16(af23[kk], bf, acc3[mt]);
            }
        }
    }

    __syncthreads();                         // all GEMM2' reads done
    float* H = (float*)Pb;                   // [64 m][68] f32
    int hb = dh * 16 + lgrp * 4;
    floatx4 b4 = *(const floatx4*)(bh1l + hb);
    #pragma unroll
    for (int mt = 0; mt < 4; mt++) {
        int m = mt * 16 + lane15;
        float gm = gats[m];
        floatx4 v;
        v[0] = fmaxf(acc3[mt][0] * gm + b4[0], 0.f);
        v[1] = fmaxf(acc3[mt][1] * gm + b4[1], 0.f);
        v[2] = fmaxf(acc3[mt][2] * gm + b4[2], 0.f);
        v[3] = fmaxf(acc3[mt][3] * gm + b4[3], 0.f);
        *(floatx4*)(H + m * 68 + hb) = v;
    }
    __syncthreads();                         // H complete

    int mloc = tid >> 2, c0 = (tid & 3) * 2;
    int tk = toks[mloc];
    float z0 = bh2l[c0], z1 = bh2l[c0 + 1];
    const floatx4* Hr4 = (const floatx4*)(H + mloc * 68);
    #pragma unroll
    for (int h4 = 0; h4 < 16; h4++) {
        floatx4 hv = Hr4[h4];
        #pragma unroll
        for (int r = 0; r < 4; r++) {
            int h = h4 * 4 + r;
            z0 += hv[r] * Wh2l[h * 8 + c0];
            z1 += hv[r] * Wh2l[h * 8 + c0 + 1];
        }
    }
    if (tk >= 0) {
        float2 rr;
        rr.x = __builtin_amdgcn_rcpf(1.0f + __expf(-z0));
        rr.y = __builtin_amdgcn_rcpf(1.0f + __expf(-z1));
        *(float2*)(result + (long)tk * 8 + c0) = rr;
    }

    // aux loss (block 0 only)
    if (bid == 0 && tid == 0) {
        const float Bf = 262144.0f;
        float tern = ternsum_g[0] * (1.0f / 1048576.0f);
        float sp = 0.f; float cp[4] = {0.f, 0.f, 0.f, 0.f};
        for (int tt = 0; tt < 16; tt++) {
            float frac = (float)cnt_g[tt] / Bf, mp = psum_g[tt] / Bf;
            sp += frac * mp; cp[tt >> 2] += mp;
        }
        float dv = 0.f;
        for (int cc = 0; cc < 4; cc++) dv += cp[cc] * logf(cp[cc] + 1e-9f);
        d_aux[0] = 0.01f * tern + 0.005f * (16.0f * sp) + 0.01f * dv;
    }
}

// ---------------- launch ----------------

extern "C" void kernel_launch(void* const* d_in, const int* in_sizes, int n_in,
                              void* d_out, int out_size, void* d_ws, size_t ws_size,
                              hipStream_t stream) {
    const int* op_idx = (const int*)d_in[0];
    const int* a_in   = (const int*)d_in[1];
    const int* b_in_i = (const int*)d_in[2];
    const int* c_in   = (const int*)d_in[3];
    const float* op_embed = (const float*)d_in[4];
    const float* W_in  = (const float*)d_in[5];
    const float* b_in  = (const float*)d_in[6];
    const float* Wr    = (const float*)d_in[7];
    const float* W1    = (const float*)d_in[8];
    const float* W2    = (const float*)d_in[9];
    const float* Wh1   = (const float*)d_in[10];
    const float* bh1   = (const float*)d_in[11];
    const float* Wh2   = (const float*)d_in[12];
    const float* bh2   = (const float*)d_in[13];

    const long B = in_sizes[0];  // 262144
    float* result = (float*)d_out;
    float* d_idx  = (float*)d_out + B * 8;
    float* d_aux  = (float*)d_out + B * 9;

    unsigned char* ws = (unsigned char*)d_ws;
    unsigned short* xq    = (unsigned short*)(ws + 0);            // 64 MB
    unsigned short* W1qT  = (unsigned short*)(ws + 67108864);     // 2 MB
    unsigned short* W23qT = (unsigned short*)(ws + 69206016);     // 1 MB
    unsigned short* Wh1T  = (unsigned short*)(ws + 70254592);     // 16 KB
    float* gate   = (float*)(ws + 70270976);                      // 1 MB
    uintx2* records = (uintx2*)(ws + 71319552);                   // 2 MB (dense)
    float* Ta    = (float*)(ws + 73416704);                       // 128 KB
    float* Tb    = (float*)(ws + 73547776);                       // 128 KB
    float* embW  = (float*)(ws + 73678848);                       // 4 KB
    float* Tc    = (float*)(ws + 73682944);                       // 512 B
    float* TaR   = (float*)(ws + 73683456);                       // 16 KB
    float* TbR   = (float*)(ws + 73699840);                       // 16 KB
    float* embWr = (float*)(ws + 73716224);                       // 512 B
    float* TcR   = (float*)(ws + 73716736);                       // 64 B
    float* partials = (float*)(ws + 73716800);                    // 2 KB
    unsigned char* acc = ws + 73718848;
    float* ternsum = (float*)(acc + 0);
    float* psum    = (float*)(acc + 64);
    int*   cnt     = (int*)(acc + 128);
    int*   fill    = (int*)(acc + 192);

    kA<<<838, 256, 0, stream>>>(W1, W2, op_embed, W_in, b_in, Wh1, Wr,
                                partials, embW, Ta, Tb, Tc, Wh1T,
                                embWr, TaR, TbR, TcR, (unsigned int*)acc);
    kB<<<640, 256, 0, stream>>>(W1, W2, partials, Wh1T, W1qT, W23qT, ternsum);
    k_front<<<1024, 256, 0, stream>>>(op_idx, a_in, b_in_i, c_in,
                                      embW, Ta, Tb, Tc, embWr, TaR, TbR, TcR,
                                      xq, gate, psum, cnt, d_idx);
    k_scatter<<<(int)(B / 256), 256, 0, stream>>>(d_idx, gate, cnt, fill, records);
    k_ffn<<<4112, 256, 37664, stream>>>(xq, records, cnt, psum, ternsum,
                                        W1qT, W23qT, Wh2, bh1, bh2, result, d_aux);
}

// Round 10
// 306.664 us; speedup vs baseline: 1.0271x; 1.0082x over previous
//
#include <hip/hip_runtime.h>
#include <hip/hip_bf16.h>
#include <math.h>

typedef __attribute__((ext_vector_type(8))) short short8;
typedef __attribute__((ext_vector_type(4))) float floatx4;
typedef __attribute__((ext_vector_type(4))) unsigned int uintx4;
typedef __attribute__((ext_vector_type(2))) unsigned int uintx2;

__device__ __forceinline__ unsigned short f2bf(float f) {
    unsigned int u = __float_as_uint(f);
    unsigned int r = (u + 0x7fffu + ((u >> 16) & 1u)) >> 16;
    return (unsigned short)r;
}

#if defined(__has_builtin)
#if __has_builtin(__builtin_amdgcn_cvt_pk_bf16_f32)
#define HAVE_PK_BF16 1
#endif
#endif

#ifdef HAVE_PK_BF16
typedef __bf16 bf16x2_t __attribute__((ext_vector_type(2)));
__device__ __forceinline__ unsigned int pk2bf(float a, float b) {
    bf16x2_t v = __builtin_amdgcn_cvt_pk_bf16_f32(a, b);
    return __builtin_bit_cast(unsigned int, v);
}
#else
__device__ __forceinline__ unsigned int pk2bf(float a, float b) {
    unsigned int ua = __float_as_uint(a);
    ua = ua + 0x7fffu + ((ua >> 16) & 1u);
    unsigned int ub = __float_as_uint(b);
    ub = ub + 0x7fffu + ((ub >> 16) & 1u);
    return (ua >> 16) | (ub & 0xffff0000u);
}
#endif

// tanh-gelu via u*sigmoid(y), Schraudolph fast exp
__device__ __forceinline__ float gelu_f(float u) {
    float u2 = u * u;
    float y = u * fmaf(u2, 0.0713548163f, 1.5957691216f);
    y = fminf(fmaxf(y, -87.0f), 87.0f);
    float f = fmaf(y, -12102203.16f, 1064866805.0f);   // bits of e^{-y}
    float e = __int_as_float((int)f);
    return u * __builtin_amdgcn_rcpf(1.0f + e);
}

__device__ __forceinline__ floatx4 mfma16(short8 a, short8 b, floatx4 c) {
    return __builtin_amdgcn_mfma_f32_16x16x32_bf16(a, b, c, 0, 0, 0);
}

// ---------------- Phase A (fused): sumabs (blocks 0-511) + tables (512-837) ----------------

__global__ __launch_bounds__(256) void kA(
        const float* __restrict__ W1, const float* __restrict__ W2,
        const float* __restrict__ op_embed, const float* __restrict__ W_in,
        const float* __restrict__ b_in, const float* __restrict__ Wh1,
        const float* __restrict__ Wr,
        float* __restrict__ partials,
        float* embW, float* Ta, float* Tb, float* Tc, unsigned short* Wh1T,
        float* embWr, float* TaR, float* TbR, float* TcR,
        unsigned int* accz) {
    if (blockIdx.x < 512) {
        int blk = blockIdx.x;
        bool isW1 = blk < 256;
        const float* W = (isW1 ? W1 : W2) + (long)(isW1 ? blk : blk - 256) * 4096;
        float s = 0.f;
        #pragma unroll
        for (int i = 0; i < 4; i++) {
            floatx4 v = *(const floatx4*)(W + i * 1024 + threadIdx.x * 4);
            s += fabsf(v[0]) + fabsf(v[1]) + fabsf(v[2]) + fabsf(v[3]);
        }
        __shared__ float red[256];
        red[threadIdx.x] = s; __syncthreads();
        for (int st = 128; st > 0; st >>= 1) {
            if (threadIdx.x < st) red[threadIdx.x] += red[threadIdx.x + st];
            __syncthreads();
        }
        if (threadIdx.x == 0) partials[blk] = red[0];
        return;
    }
    int bidT = blockIdx.x - 512;
    if (bidT == 0 && threadIdx.x < 64) accz[threadIdx.x] = 0u;  // zero acc region
    if (bidT < 293) {
        int i = bidT * 256 + threadIdx.x;
        if (i < 1024) {
            int op = i >> 7, j = i & 127;
            float s = b_in[j];
            #pragma unroll
            for (int k = 0; k < 32; k++) s += op_embed[op * 32 + k] * W_in[k * 128 + j];
            embW[i] = s;
        } else if (i < 1024 + 32768) {
            int r = i - 1024; int a = r >> 7, j = r & 127;
            float s = 0.f;
            #pragma unroll
            for (int bit = 0; bit < 8; bit++) if ((a >> bit) & 1) s += W_in[(32 + bit) * 128 + j];
            Ta[r] = s;
        } else if (i < 33792 + 32768) {
            int r = i - 33792; int b = r >> 7, j = r & 127;
            float s = 0.f;
            #pragma unroll
            for (int bit = 0; bit < 8; bit++) if ((b >> bit) & 1) s += W_in[(40 + bit) * 128 + j];
            Tb[r] = s;
        } else if (i < 66560 + 128) {
            int j = i - 66560; Tc[j] = W_in[48 * 128 + j];
        } else if (i < 66688 + 8192) {
            int r = i - 66688; int h = r >> 7, k = r & 127;
            Wh1T[r] = f2bf(Wh1[k * 64 + h]);
        }
    } else {
        int jdx = (bidT - 293) * 256 + threadIdx.x;
        if (jdx < 4096) {            // TaR[a][t]
            int a = jdx >> 4, t = jdx & 15;
            float s = 0.f;
            for (int j = 0; j < 128; j++) {
                float ta = 0.f;
                #pragma unroll
                for (int bit = 0; bit < 8; bit++)
                    if ((a >> bit) & 1) ta += W_in[(32 + bit) * 128 + j];
                s += ta * Wr[j * 16 + t];
            }
            TaR[jdx] = s;
        } else if (jdx < 8192) {     // TbR[b][t]
            int r = jdx - 4096; int b = r >> 4, t = r & 15;
            float s = 0.f;
            for (int j = 0; j < 128; j++) {
                float tb = 0.f;
                #pragma unroll
                for (int bit = 0; bit < 8; bit++)
                    if ((b >> bit) & 1) tb += W_in[(40 + bit) * 128 + j];
                s += tb * Wr[j * 16 + t];
            }
            TbR[r] = s;
        } else if (jdx < 8320) {     // embWr[op][t]
            int e = jdx - 8192; int op = e >> 4, t = e & 15;
            float s = 0.f;
            for (int j = 0; j < 128; j++) {
                float ej = b_in[j];
                #pragma unroll
                for (int k = 0; k < 32; k++) ej += op_embed[op * 32 + k] * W_in[k * 128 + j];
                s += ej * Wr[j * 16 + t];
            }
            embWr[e] = s;
        } else if (jdx < 8336) {     // TcR[t]
            int t = jdx - 8320;
            float s = 0.f;
            for (int j = 0; j < 128; j++) s += W_in[48 * 128 + j] * Wr[j * 16 + t];
            TcR[t] = s;
        }
    }
}

// ---------------- Phase A2+B (fused): W1 quant (0-511) + W23 (512-639) + router (640-1663) ----

__global__ __launch_bounds__(256) void kBF(
        const float* __restrict__ W1, const float* __restrict__ W2,
        const float* __restrict__ partials, const unsigned short* __restrict__ Wh1T,
        unsigned short* __restrict__ W1qT, unsigned short* __restrict__ W23qT,
        float* ternsum,
        const int* __restrict__ op_idx, const int* __restrict__ a_in,
        const int* __restrict__ b_in_i, const int* __restrict__ c_in,
        const float* __restrict__ embWr, const float* __restrict__ TaR,
        const float* __restrict__ TbR, const float* __restrict__ TcR,
        float* __restrict__ gate_out, float* psum, int* cnt,
        float* __restrict__ d_idx) {
    __shared__ unsigned short lt[64 * 40];
    __shared__ float red[256];
    __shared__ float sp[4][16];
    __shared__ int sc[4][16];
    int tid = threadIdx.x;

    if (blockIdx.x < 512) {
        // W1 quant+transpose: 16 t x 8 n0 x 4 dq
        float dsum = 0.f;
        int bid = blockIdx.x;
        int t = bid >> 5, sub = bid & 31;
        int n0 = (sub >> 2) * 64, dq = sub & 3;
        const float* part = partials + t * 16;
        float ssum = 0.f;
        #pragma unroll
        for (int i = 0; i < 16; i++) ssum += part[i];
        float s = ssum * (1.0f / 65536.0f);
        float thr = 0.7f * s;
        const float* Wt = W1 + (long)t * 65536 + (long)dq * 32 * 512;
        int j = tid & 63, d4 = tid >> 6;
        #pragma unroll
        for (int it = 0; it < 8; it++) {
            int d = it * 4 + d4;
            float w = Wt[d * 512 + n0 + j];
            float q = (fabsf(w) > thr) ? (w > 0.f ? s : -s) : 0.f;
            dsum += fabsf(w - q);
            lt[j * 40 + d] = f2bf(q);
        }
        __syncthreads();
        int n = tid >> 2, ds = (tid & 3) * 8;
        *(uintx4*)(W1qT + (long)t * 65536 + (n0 + n) * 128 + dq * 32 + ds) =
            *(const uintx4*)(lt + n * 40 + ds);

        red[tid] = dsum; __syncthreads();
        for (int st2 = 128; st2 > 0; st2 >>= 1) {
            if (tid < st2) red[tid] += red[tid + st2];
            __syncthreads();
        }
        if (tid == 0) atomicAdd(ternsum, red[0]);
        return;
    }
    if (blockIdx.x < 640) {
        // W23qT[t][h][n] = (W2q[t] @ Wh1)^T; W2 quantized on the fly
        float dsum = 0.f;
        int bid = blockIdx.x - 512;
        int t = bid >> 3, n0 = (bid & 7) * 64;
        int lane = tid & 63, w = tid >> 6;
        int lane15 = lane & 15, lgrp = lane >> 4;

        const float* part = partials + 256 + t * 16;
        float ssum = 0.f;
        #pragma unroll
        for (int i = 0; i < 16; i++) ssum += part[i];
        float s = ssum * (1.0f / 65536.0f);
        float thr = 0.7f * s;

        int n = n0 + w * 16 + lane15;
        const float* w2row = W2 + (long)t * 65536 + n * 128 + lgrp * 8;
        short8 bfr[4];
        #pragma unroll
        for (int kk = 0; kk < 4; kk++) {
            floatx4 v0 = *(const floatx4*)(w2row + kk * 32);
            floatx4 v1 = *(const floatx4*)(w2row + kk * 32 + 4);
            float q[8];
            #pragma unroll
            for (int r = 0; r < 4; r++) {
                q[r]     = (fabsf(v0[r]) > thr) ? (v0[r] > 0.f ? s : -s) : 0.f;
                q[r + 4] = (fabsf(v1[r]) > thr) ? (v1[r] > 0.f ? s : -s) : 0.f;
                dsum += fabsf(v0[r] - q[r]) + fabsf(v1[r] - q[r + 4]);
            }
            uintx4 o;
            o[0] = pk2bf(q[0], q[1]); o[1] = pk2bf(q[2], q[3]);
            o[2] = pk2bf(q[4], q[5]); o[3] = pk2bf(q[6], q[7]);
            bfr[kk] = __builtin_bit_cast(short8, o);
        }

        floatx4 acc[4];
        #pragma unroll
        for (int i = 0; i < 4; i++) acc[i] = (floatx4){0.f, 0.f, 0.f, 0.f};
        #pragma unroll
        for (int kk = 0; kk < 4; kk++) {
            #pragma unroll
            for (int ht = 0; ht < 4; ht++) {
                short8 af = *(const short8*)(Wh1T + (ht * 16 + lane15) * 128 + lgrp * 8 + kk * 32);
                acc[ht] = mfma16(af, bfr[kk], acc[ht]);
            }
        }
        #pragma unroll
        for (int ht = 0; ht < 4; ht++) {
            #pragma unroll
            for (int r = 0; r < 4; r++) {
                int h = ht * 16 + lgrp * 4 + r;
                W23qT[((long)t * 64 + h) * 512 + n] = f2bf(acc[ht][r]);
            }
        }

        red[tid] = dsum; __syncthreads();
        for (int st2 = 128; st2 > 0; st2 >>= 1) {
            if (tid < st2) red[tid] += red[tid + st2];
            __syncthreads();
        }
        if (tid == 0) atomicAdd(ternsum, red[0]);
        return;
    }

    // ---- router-only front: 1024 blocks, 16 lanes/token, 16 iters ----
    int gid = (blockIdx.x - 640) * 256 + tid;
    int lane = tid & 63;
    int j = lane & 15;
    int grpbase = lane & 48;
    float psum_acc = 0.f; int cnt_acc = 0;

    #pragma unroll 1
    for (int it = 0; it < 16; it++) {
        int tok = it * 16384 + (gid >> 4);
        int op = op_idx[tok], a = a_in[tok], b = b_in_i[tok], c = c_in[tok];
        float cf = (float)c;

        float lg = embWr[op * 16 + j] + TaR[a * 16 + j] + TbR[b * 16 + j] + cf * TcR[j];
        float m = lg;
        m = fmaxf(m, __shfl_xor(m, 8, 16));
        m = fmaxf(m, __shfl_xor(m, 4, 16));
        m = fmaxf(m, __shfl_xor(m, 2, 16));
        m = fmaxf(m, __shfl_xor(m, 1, 16));
        float p = __expf(lg - m);
        float sm = p;
        sm += __shfl_xor(sm, 8, 16);
        sm += __shfl_xor(sm, 4, 16);
        sm += __shfl_xor(sm, 2, 16);
        sm += __shfl_xor(sm, 1, 16);
        float g = __builtin_amdgcn_rcpf(sm);
        unsigned long long ball = __ballot(lg == m);
        int bi = __ffsll((unsigned long long)((ball >> grpbase) & 0xffffULL)) - 1;
        psum_acc += p * g;
        cnt_acc += (j == bi) ? 1 : 0;
        if (j == 0) { gate_out[tok] = g; d_idx[tok] = (float)bi; }
    }

    psum_acc += __shfl_xor(psum_acc, 16);
    psum_acc += __shfl_xor(psum_acc, 32);
    cnt_acc += __shfl_xor(cnt_acc, 16);
    cnt_acc += __shfl_xor(cnt_acc, 32);
    int wv = tid >> 6;
    if (lane < 16) { sp[wv][j] = psum_acc; sc[wv][j] = cnt_acc; }
    __syncthreads();
    if (tid < 16) {
        atomicAdd(&psum[tid], sp[0][tid] + sp[1][tid] + sp[2][tid] + sp[3][tid]);
        atomicAdd(&cnt[tid], sc[0][tid] + sc[1][tid] + sc[2][tid] + sc[3][tid]);
    }
}

// ---------------- scatter: packed {tok, gate} records at EXACT dense offsets ----------------

__global__ void k_scatter(const float* __restrict__ d_idx, const float* __restrict__ gate,
                          const int* __restrict__ cnt,
                          int* fill, uintx2* __restrict__ records) {
    __shared__ int lc[16], lbase[16];
    if (threadIdx.x < 16) lc[threadIdx.x] = 0;
    __syncthreads();
    int offs[16];
    {
        int off = 0;
        #pragma unroll
        for (int tt = 0; tt < 16; tt++) { offs[tt] = off; off += cnt[tt]; }
    }
    int tok = blockIdx.x * 256 + threadIdx.x;
    int t = (int)d_idx[tok];
    int lpos = atomicAdd(&lc[t], 1);
    __syncthreads();
    if (threadIdx.x < 16) lbase[threadIdx.x] = atomicAdd(&fill[threadIdx.x], lc[threadIdx.x]);
    __syncthreads();
    uintx2 rec;
    rec[0] = (unsigned)tok;
    rec[1] = __float_as_uint(gate[tok]);
    records[offs[t] + lbase[t] + lpos] = rec;
}

// ---------------- Phase C: MoE FFN + fused head; X computed in-block from tables ----------

__global__ __launch_bounds__(256, 4) void k_ffn(
    const int* __restrict__ op_idx, const int* __restrict__ a_in,
    const int* __restrict__ b_in_i, const int* __restrict__ c_in,
    const float* __restrict__ embW, const float* __restrict__ Ta,
    const float* __restrict__ Tb, const float* __restrict__ Tc,
    const uintx2* __restrict__ recs, const int* __restrict__ cnt_g,
    const float* __restrict__ psum_g, const float* __restrict__ ternsum_g,
    const unsigned short* __restrict__ W1qT, const unsigned short* __restrict__ W23qT,
    const float* __restrict__ Wh2, const float* __restrict__ bh1,
    const float* __restrict__ bh2,
    float* __restrict__ result, float* __restrict__ d_aux) {

    extern __shared__ __align__(16) unsigned char smem[];
    unsigned short* Ax = (unsigned short*)smem;            // [64][136] bf16
    unsigned short* Pb = Ax + 64 * 136;                    // [64][136] bf16; later H f32 [64][68]
    int*   toks = (int*)(smem + 34816);
    float* gats = (float*)(smem + 35072);
    float* Wh2l = (float*)(smem + 35328);                  // 512 f
    float* bh2l = (float*)(smem + 37376);                  // 8 f
    float* bh1l = (float*)(smem + 37408);                  // 64 f
    int*   opl  = (int*)(smem + 37664);                    // 64 i
    int*   al   = (int*)(smem + 37920);                    // 64 i
    int*   bl   = (int*)(smem + 38176);                    // 64 i
    float* cfl  = (float*)(smem + 38432);                  // 64 f

    int bid = blockIdx.x;
    int t = -1, ci = 0, nt = 0, base = 0;
    {
        int coff = 0, off = 0;
        #pragma unroll 1
        for (int tt = 0; tt < 16; tt++) {
            int c = cnt_g[tt];
            int ch = (c + 63) >> 6;
            if (t < 0 && bid < coff + ch) { t = tt; ci = bid - coff; nt = c; base = off + ci * 64; }
            coff += ch; off += c;
        }
    }
    if (t < 0) return;
    int nvalid = nt - ci * 64; if (nvalid > 64) nvalid = 64;

    int tid = threadIdx.x;
    if (tid < 64) {
        uintx2 rec = {0xFFFFFFFFu, 0u};
        if (tid < nvalid) rec = recs[base + tid];
        int tk = (int)rec[0];
        toks[tid] = tk;
        gats[tid] = __uint_as_float(rec[1]);
        if (tk >= 0) {
            opl[tid] = op_idx[tk]; al[tid] = a_in[tk];
            bl[tid] = b_in_i[tk];  cfl[tid] = (float)c_in[tk];
        } else {
            opl[tid] = 0; al[tid] = 0; bl[tid] = 0; cfl[tid] = 0.f;
        }
    }
    Wh2l[tid] = Wh2[tid];
    Wh2l[tid + 256] = Wh2[tid + 256];
    if (tid < 8) bh2l[tid] = bh2[tid];
    else if (tid < 72) bh1l[tid - 8] = bh1[tid - 8];
    __syncthreads();

    // compute X tile from tables directly into LDS (identical arithmetic to old k_front)
    #pragma unroll
    for (int it = 0; it < 4; it++) {
        int seg = it * 256 + tid; int r = seg >> 4, sg = seg & 15;
        int tk = toks[r];
        uintx4 o = {0u, 0u, 0u, 0u};
        if (tk >= 0) {
            int op = opl[r], a = al[r], b = bl[r];
            float cf = cfl[r];
            int d0 = sg * 8;
            const floatx4* E  = (const floatx4*)(embW + op * 128 + d0);
            const floatx4* A4 = (const floatx4*)(Ta + a * 128 + d0);
            const floatx4* B4 = (const floatx4*)(Tb + b * 128 + d0);
            const floatx4* C4 = (const floatx4*)(Tc + d0);
            floatx4 v0 = E[0] + A4[0] + B4[0] + cf * C4[0];
            floatx4 v1 = E[1] + A4[1] + B4[1] + cf * C4[1];
            o[0] = pk2bf(v0[0], v0[1]);
            o[1] = pk2bf(v0[2], v0[3]);
            o[2] = pk2bf(v1[0], v1[1]);
            o[3] = pk2bf(v1[2], v1[3]);
        }
        *(uintx4*)(Ax + r * 136 + sg * 8) = o;
    }
    __syncthreads();

    int lane = tid & 63, dh = tid >> 6;
    int lane15 = lane & 15, lgrp = lane >> 4;

    floatx4 acc3[4];
    #pragma unroll
    for (int jj = 0; jj < 4; jj++) acc3[jj] = (floatx4){0.f, 0.f, 0.f, 0.f};

    const unsigned short* w1p = W1qT + (long)t * 65536 + lgrp * 8;
    const unsigned short* w23p = W23qT + ((long)t * 64 + dh * 16 + lane15) * 512 + lgrp * 8;

    for (int nc = 0; nc < 4; nc++) {
        const unsigned short* w23c = w23p + nc * 128;
        short8 af23[4];
        #pragma unroll
        for (int kk = 0; kk < 4; kk++) af23[kk] = *(const short8*)(w23c + kk * 32);

        floatx4 acc1[2][4];
        #pragma unroll
        for (int i = 0; i < 2; i++)
            #pragma unroll
            for (int jj = 0; jj < 4; jj++) acc1[i][jj] = (floatx4){0.f, 0.f, 0.f, 0.f};

        const unsigned short* w1c = w1p + (long)nc * 16384 + (dh * 32 + lane15) * 128;
        #pragma unroll
        for (int kk = 0; kk < 4; kk++) {
            short8 af0 = *(const short8*)(w1c + kk * 32);
            short8 af1 = *(const short8*)(w1c + 2048 + kk * 32);
            int ko = kk * 32 + lgrp * 8;
            #pragma unroll
            for (int mt = 0; mt < 4; mt++) {
                short8 bf = *(const short8*)(Ax + (mt * 16 + lane15) * 136 + ko);
                acc1[0][mt] = mfma16(af0, bf, acc1[0][mt]);
                acc1[1][mt] = mfma16(af1, bf, acc1[1][mt]);
            }
        }
        __syncthreads();                     // prev GEMM2' Pb reads done

        #pragma unroll
        for (int i = 0; i < 2; i++) {
            int k2b = dh * 32 + i * 16 + lgrp * 4;
            #pragma unroll
            for (int mt = 0; mt < 4; mt++) {
                int m = mt * 16 + lane15;
                floatx4 v = acc1[i][mt];
                float g0 = gelu_f(v[0]), g1v = gelu_f(v[1]);
                float g2v = gelu_f(v[2]), g3 = gelu_f(v[3]);
                uintx2 o; o[0] = pk2bf(g0, g1v); o[1] = pk2bf(g2v, g3);
                *(uintx2*)(Pb + m * 136 + k2b) = o;
            }
        }
        __syncthreads();                     // Pb ready

        #pragma unroll
        for (int kk = 0; kk < 4; kk++) {
            int ko = kk * 32 + lgrp * 8;
            #pragma unroll
            for (int mt = 0; mt < 4; mt++) {
                short8 bf = *(const short8*)(Pb + (mt * 16 + lane15) * 136 + ko);
                acc3[mt] = mfma16(af23[kk], bf, acc3[mt]);
            }
        }
    }

    __syncthreads();                         // all GEMM2' reads done
    float* H = (float*)Pb;                   // [64 m][68] f32
    int hb = dh * 16 + lgrp * 4;
    floatx4 b4 = *(const floatx4*)(bh1l + hb);
    #pragma unroll
    for (int mt = 0; mt < 4; mt++) {
        int m = mt * 16 + lane15;
        float gm = gats[m];
        floatx4 v;
        v[0] = fmaxf(acc3[mt][0] * gm + b4[0], 0.f);
        v[1] = fmaxf(acc3[mt][1] * gm + b4[1], 0.f);
        v[2] = fmaxf(acc3[mt][2] * gm + b4[2], 0.f);
        v[3] = fmaxf(acc3[mt][3] * gm + b4[3], 0.f);
        *(floatx4*)(H + m * 68 + hb) = v;
    }
    __syncthreads();                         // H complete

    int mloc = tid >> 2, c0 = (tid & 3) * 2;
    int tk = toks[mloc];
    float z0 = bh2l[c0], z1 = bh2l[c0 + 1];
    const floatx4* Hr4 = (const floatx4*)(H + mloc * 68);
    #pragma unroll
    for (int h4 = 0; h4 < 16; h4++) {
        floatx4 hv = Hr4[h4];
        #pragma unroll
        for (int r = 0; r < 4; r++) {
            int h = h4 * 4 + r;
            z0 += hv[r] * Wh2l[h * 8 + c0];
            z1 += hv[r] * Wh2l[h * 8 + c0 + 1];
        }
    }
    if (tk >= 0) {
        float2 rr;
        rr.x = __builtin_amdgcn_rcpf(1.0f + __expf(-z0));
        rr.y = __builtin_amdgcn_rcpf(1.0f + __expf(-z1));
        *(float2*)(result + (long)tk * 8 + c0) = rr;
    }

    // aux loss (block 0 only)
    if (bid == 0 && tid == 0) {
        const float Bf = 262144.0f;
        float tern = ternsum_g[0] * (1.0f / 1048576.0f);
        float sp = 0.f; float cp[4] = {0.f, 0.f, 0.f, 0.f};
        for (int tt = 0; tt < 16; tt++) {
            float frac = (float)cnt_g[tt] / Bf, mp = psum_g[tt] / Bf;
            sp += frac * mp; cp[tt >> 2] += mp;
        }
        float dv = 0.f;
        for (int cc = 0; cc < 4; cc++) dv += cp[cc] * logf(cp[cc] + 1e-9f);
        d_aux[0] = 0.01f * tern + 0.005f * (16.0f * sp) + 0.01f * dv;
    }
}

// ---------------- launch ----------------

extern "C" void kernel_launch(void* const* d_in, const int* in_sizes, int n_in,
                              void* d_out, int out_size, void* d_ws, size_t ws_size,
                              hipStream_t stream) {
    const int* op_idx = (const int*)d_in[0];
    const int* a_in   = (const int*)d_in[1];
    const int* b_in_i = (const int*)d_in[2];
    const int* c_in   = (const int*)d_in[3];
    const float* op_embed = (const float*)d_in[4];
    const float* W_in  = (const float*)d_in[5];
    const float* b_in  = (const float*)d_in[6];
    const float* Wr    = (const float*)d_in[7];
    const float* W1    = (const float*)d_in[8];
    const float* W2    = (const float*)d_in[9];
    const float* Wh1   = (const float*)d_in[10];
    const float* bh1   = (const float*)d_in[11];
    const float* Wh2   = (const float*)d_in[12];
    const float* bh2   = (const float*)d_in[13];

    const long B = in_sizes[0];  // 262144
    float* result = (float*)d_out;
    float* d_idx  = (float*)d_out + B * 8;
    float* d_aux  = (float*)d_out + B * 9;

    unsigned char* ws = (unsigned char*)d_ws;
    unsigned short* W1qT  = (unsigned short*)(ws + 0);            // 2 MB
    unsigned short* W23qT = (unsigned short*)(ws + 2097152);      // 1 MB
    unsigned short* Wh1T  = (unsigned short*)(ws + 3145728);      // 16 KB
    float* gate   = (float*)(ws + 3162112);                       // 1 MB
    uintx2* records = (uintx2*)(ws + 4210688);                    // 2 MB (dense)
    float* Ta    = (float*)(ws + 6307840);                        // 128 KB
    float* Tb    = (float*)(ws + 6438912);                        // 128 KB
    float* embW  = (float*)(ws + 6569984);                        // 4 KB
    float* Tc    = (float*)(ws + 6574080);                        // 512 B
    float* TaR   = (float*)(ws + 6574592);                        // 16 KB
    float* TbR   = (float*)(ws + 6590976);                        // 16 KB
    float* embWr = (float*)(ws + 6607360);                        // 512 B
    float* TcR   = (float*)(ws + 6607872);                        // 64 B
    float* partials = (float*)(ws + 6607936);                     // 2 KB
    unsigned char* acc = ws + 6609984;
    float* ternsum = (float*)(acc + 0);
    float* psum    = (float*)(acc + 64);
    int*   cnt     = (int*)(acc + 128);
    int*   fill    = (int*)(acc + 192);

    kA<<<838, 256, 0, stream>>>(W1, W2, op_embed, W_in, b_in, Wh1, Wr,
                                partials, embW, Ta, Tb, Tc, Wh1T,
                                embWr, TaR, TbR, TcR, (unsigned int*)acc);
    kBF<<<1664, 256, 0, stream>>>(W1, W2, partials, Wh1T, W1qT, W23qT, ternsum,
                                  op_idx, a_in, b_in_i, c_in,
                                  embWr, TaR, TbR, TcR,
                                  gate, psum, cnt, d_idx);
    k_scatter<<<(int)(B / 256), 256, 0, stream>>>(d_idx, gate, cnt, fill, records);
    k_ffn<<<4112, 256, 38688, stream>>>(op_idx, a_in, b_in_i, c_in,
                                        embW, Ta, Tb, Tc,
                                        records, cnt, psum, ternsum,
                                        W1qT, W23qT, Wh2, bh1, bh2, result, d_aux);
}